// Round 1
// baseline (357.368 us; speedup 1.0000x reference)
//
#include <hip/hip_runtime.h>

// ---------------------------------------------------------------------------
// ReLU zonotope transformer.
//   x: [K, F] fp32 (row 0 = center), lambdas: [1, F] fp32
//   out: [K+F, F] fp32 = [scaled zonotope ; diag(half) extension]
// Memory-bound: ~302 MB of mandatory writes (ext block is poisoned each call).
// ---------------------------------------------------------------------------

#define BLK 256

// Kernel 1: partial column-wise sum of |x[1:]| over row chunks.
// grid = (f4/BLK, CHUNKS); each thread handles 4 columns (float4) x rpc rows.
__global__ void k_partial_abssum(const float4* __restrict__ x4,
                                 float4* __restrict__ partial4,
                                 int f4, int rows, int rpc) {
    int col4  = blockIdx.x * BLK + threadIdx.x;     // float4-column index
    int chunk = blockIdx.y;
    int r0 = chunk * rpc;
    int r1 = r0 + rpc;
    if (r1 > rows) r1 = rows;
    float4 s = make_float4(0.f, 0.f, 0.f, 0.f);
    for (int r = r0; r < r1; ++r) {
        float4 v = x4[(size_t)(1 + r) * f4 + col4]; // rows 1..K-1 (error terms)
        s.x += fabsf(v.x);
        s.y += fabsf(v.y);
        s.z += fabsf(v.z);
        s.w += fabsf(v.w);
    }
    partial4[(size_t)chunk * f4 + col4] = s;
}

// Kernel 2: reduce partials per column, compute scale[f] and half[f].
__global__ void k_finalize(const float* __restrict__ partial,
                           int chunks,
                           const float* __restrict__ x,        // row 0 = center
                           const float* __restrict__ lambdas,
                           float* __restrict__ scale,
                           float* __restrict__ half_,
                           int F) {
    int col = blockIdx.x * BLK + threadIdx.x;
    if (col >= F) return;
    float s = 0.f;
    for (int c = 0; c < chunks; ++c)
        s += partial[(size_t)c * F + col];
    float cen = x[col];
    float l = cen - s;
    float u = cen + s;
    float la = lambdas[col];
    float pos   = (l > 0.f) ? 1.f : 0.f;
    float cross = (u > 0.f && l < 0.f) ? 1.f : 0.f;
    float d = fmaxf(-l * la, u * (1.f - la));
    scale[col] = pos + cross * la;
    half_[col] = 0.5f * cross * d;
}

// Kernel 3: out[k][f] = scale[f] * x[k][f]; row 0 adds half[f].
// grid = (f4/BLK, K); row = blockIdx.y (no integer division anywhere).
__global__ void k_scale_rows(const float4* __restrict__ x4,
                             const float4* __restrict__ scale4,
                             const float4* __restrict__ half4,
                             float4* __restrict__ out4,
                             int f4) {
    int col4 = blockIdx.x * BLK + threadIdx.x;
    int row  = blockIdx.y;
    float4 v = x4[(size_t)row * f4 + col4];
    float4 s = scale4[col4];
    float4 o;
    o.x = v.x * s.x;
    o.y = v.y * s.y;
    o.z = v.z * s.z;
    o.w = v.w * s.w;
    if (row == 0) {
        float4 h = half4[col4];
        o.x += h.x; o.y += h.y; o.z += h.z; o.w += h.w;
    }
    out4[(size_t)row * f4 + col4] = o;
}

// Kernel 4: ext block = zeros with diag(half) fused in.
// grid = F blocks; block b owns ext row b (f4 float4 stores).
__global__ void k_write_ext(float4* __restrict__ ext4,
                            const float* __restrict__ half_,
                            int f4) {
    int row   = blockIdx.x;
    int diag4 = row >> 2;            // which float4 of this row holds the diag
    int lane  = row & 3;
    float hv  = half_[row];          // broadcast load
    size_t base = (size_t)row * f4;
    for (int c4 = threadIdx.x; c4 < f4; c4 += BLK) {
        float4 z = make_float4(0.f, 0.f, 0.f, 0.f);
        if (c4 == diag4) {
            ((float*)&z)[lane] = hv;
        }
        ext4[base + c4] = z;
    }
}

extern "C" void kernel_launch(void* const* d_in, const int* in_sizes, int n_in,
                              void* d_out, int out_size, void* d_ws, size_t ws_size,
                              hipStream_t stream) {
    const float* x       = (const float*)d_in[0];
    const float* lambdas = (const float*)d_in[1];

    const int F    = in_sizes[1];          // 8192
    const int K    = in_sizes[0] / F;      // 1025
    const int f4   = F / 4;                // 2048
    const int rows = K - 1;                // 1024 error-term rows

    const int CHUNKS = 64;
    const int rpc = (rows + CHUNKS - 1) / CHUNKS;   // 16

    // Workspace layout (floats): [half F][scale F][partials CHUNKS*F]
    float* wsf     = (float*)d_ws;
    float* half_   = wsf;
    float* scale   = wsf + F;
    float* partial = wsf + 2 * (size_t)F;

    float* out = (float*)d_out;
    float* ext = out + (size_t)K * F;

    const float4* x4 = (const float4*)x;

    // 1. partial |x| column sums
    k_partial_abssum<<<dim3(f4 / BLK, CHUNKS), BLK, 0, stream>>>(
        x4, (float4*)partial, f4, rows, rpc);

    // 2. reduce partials -> scale[F], half[F]
    k_finalize<<<dim3((F + BLK - 1) / BLK), BLK, 0, stream>>>(
        partial, CHUNKS, x, lambdas, scale, half_, F);

    // 3. scaled zonotope rows (+half on center row)
    k_scale_rows<<<dim3(f4 / BLK, K), BLK, 0, stream>>>(
        x4, (const float4*)scale, (const float4*)half_, (float4*)out, f4);

    // 4. ext block: zeros + diag(half)
    k_write_ext<<<dim3(F), BLK, 0, stream>>>(
        (float4*)ext, half_, f4);
}

// Round 3
// 341.279 us; speedup vs baseline: 1.0471x; 1.0471x over previous
//
#include <hip/hip_runtime.h>

// ---------------------------------------------------------------------------
// ReLU zonotope transformer.
//   x: [K, F] fp32 (row 0 = center), lambdas: [1, F] fp32
//   out: [K+F, F] fp32 = [scaled zonotope ; diag(half) extension]
// Memory-bound: ~302 MB of mandatory writes. The 256 MB ext block is zeroed
// via hipMemsetAsync (captures as the rocclr fill kernel, measured 6.2 TB/s)
// and the 8192 diagonal values are scattered afterwards.
// ---------------------------------------------------------------------------

#define BLK 256

// Native vector type for nontemporal stores (clang builtin rejects the
// HIP_vector_type class wrapper).
typedef float v4f __attribute__((ext_vector_type(4)));

// Kernel 1: partial column-wise sum of |x[1:]| over row chunks.
// grid = (f4/BLK, CHUNKS); each thread handles 4 columns (float4) x rpc rows.
__global__ void k_partial_abssum(const float4* __restrict__ x4,
                                 float4* __restrict__ partial4,
                                 int f4, int rows, int rpc) {
    int col4  = blockIdx.x * BLK + threadIdx.x;     // float4-column index
    int chunk = blockIdx.y;
    int r0 = chunk * rpc;
    int r1 = r0 + rpc;
    if (r1 > rows) r1 = rows;
    float4 s = make_float4(0.f, 0.f, 0.f, 0.f);
    for (int r = r0; r < r1; ++r) {
        float4 v = x4[(size_t)(1 + r) * f4 + col4]; // rows 1..K-1 (error terms)
        s.x += fabsf(v.x);
        s.y += fabsf(v.y);
        s.z += fabsf(v.z);
        s.w += fabsf(v.w);
    }
    partial4[(size_t)chunk * f4 + col4] = s;
}

// Kernel 2: reduce partials per column, compute scale[f] and half[f].
__global__ void k_finalize(const float* __restrict__ partial,
                           int chunks,
                           const float* __restrict__ x,        // row 0 = center
                           const float* __restrict__ lambdas,
                           float* __restrict__ scale,
                           float* __restrict__ half_,
                           int F) {
    int col = blockIdx.x * BLK + threadIdx.x;
    if (col >= F) return;
    float s = 0.f;
    for (int c = 0; c < chunks; ++c)
        s += partial[(size_t)c * F + col];
    float cen = x[col];
    float l = cen - s;
    float u = cen + s;
    float la = lambdas[col];
    float pos   = (l > 0.f) ? 1.f : 0.f;
    float cross = (u > 0.f && l < 0.f) ? 1.f : 0.f;
    float d = fmaxf(-l * la, u * (1.f - la));
    scale[col] = pos + cross * la;
    half_[col] = 0.5f * cross * d;
}

// Kernel 3: out[k][f] = scale[f] * x[k][f]; row 0 adds half[f].
// grid = (f4/BLK, K); row = blockIdx.y (no integer division anywhere).
__global__ void k_scale_rows(const float4* __restrict__ x4,
                             const float4* __restrict__ scale4,
                             const float4* __restrict__ half4,
                             v4f* __restrict__ out4,
                             int f4) {
    int col4 = blockIdx.x * BLK + threadIdx.x;
    int row  = blockIdx.y;
    float4 v = x4[(size_t)row * f4 + col4];
    float4 s = scale4[col4];
    v4f o;
    o.x = v.x * s.x;
    o.y = v.y * s.y;
    o.z = v.z * s.z;
    o.w = v.w * s.w;
    if (row == 0) {
        float4 h = half4[col4];
        o.x += h.x; o.y += h.y; o.z += h.z; o.w += h.w;
    }
    __builtin_nontemporal_store(o, &out4[(size_t)row * f4 + col4]);
}

// Kernel 4: scatter the F diagonal values into the (already zeroed) ext block.
// ext[i*F + i] = half_[i]. Only F=8192 scattered 4B stores — negligible.
__global__ void k_diag(float* __restrict__ ext,
                       const float* __restrict__ half_,
                       int F) {
    int i = blockIdx.x * BLK + threadIdx.x;
    if (i < F) {
        ext[(size_t)i * F + i] = half_[i];
    }
}

extern "C" void kernel_launch(void* const* d_in, const int* in_sizes, int n_in,
                              void* d_out, int out_size, void* d_ws, size_t ws_size,
                              hipStream_t stream) {
    const float* x       = (const float*)d_in[0];
    const float* lambdas = (const float*)d_in[1];

    const int F    = in_sizes[1];          // 8192
    const int K    = in_sizes[0] / F;      // 1025
    const int f4   = F / 4;                // 2048
    const int rows = K - 1;                // 1024 error-term rows

    const int CHUNKS = 64;
    const int rpc = (rows + CHUNKS - 1) / CHUNKS;   // 16

    // Workspace layout (floats): [half F][scale F][partials CHUNKS*F]
    float* wsf     = (float*)d_ws;
    float* half_   = wsf;
    float* scale   = wsf + F;
    float* partial = wsf + 2 * (size_t)F;

    float* out = (float*)d_out;
    float* ext = out + (size_t)K * F;

    const float4* x4 = (const float4*)x;

    // Bulk-zero the ext block at fill speed (6.2 TB/s measured for this path).
    (void)hipMemsetAsync(ext, 0, (size_t)F * F * sizeof(float), stream);

    // 1. partial |x| column sums
    k_partial_abssum<<<dim3(f4 / BLK, CHUNKS), BLK, 0, stream>>>(
        x4, (float4*)partial, f4, rows, rpc);

    // 2. reduce partials -> scale[F], half[F]
    k_finalize<<<dim3((F + BLK - 1) / BLK), BLK, 0, stream>>>(
        partial, CHUNKS, x, lambdas, scale, half_, F);

    // 3. scaled zonotope rows (+half on center row)
    k_scale_rows<<<dim3(f4 / BLK, K), BLK, 0, stream>>>(
        x4, (const float4*)scale, (const float4*)half_, (v4f*)out, f4);

    // 4. diagonal scatter into ext
    k_diag<<<dim3((F + BLK - 1) / BLK), BLK, 0, stream>>>(ext, half_, F);
}

// Round 4
// 336.439 us; speedup vs baseline: 1.0622x; 1.0144x over previous
//
#include <hip/hip_runtime.h>

// ---------------------------------------------------------------------------
// ReLU zonotope transformer.
//   x: [K, F] fp32 (row 0 = center), lambdas: [1, F] fp32
//   out: [K+F, F] fp32 = [scaled zonotope ; diag(half) extension]
//
// dur_us decomposition (R1/R3 evidence): ~280 us fixed harness overhead
// (1.2 GB re-poison fill @190 us is inside the timed window) + our kernels.
// Our floor: 302 MB writes + 33.5 MB read @ ~6.4 TB/s ~= 53 us.
// Structure: 1 reduce pass + tiny finalize + ONE fused writer (out rows,
// ext zeros, and diagonal all in a single dispatch, NT stores).
// ---------------------------------------------------------------------------

#define BLK 256

// Native vector type for nontemporal stores (clang builtin rejects the
// HIP_vector_type class wrapper).
typedef float v4f __attribute__((ext_vector_type(4)));

// Kernel 1: partial column-wise sum of |x[1:]| over row chunks.
// grid = (f4/BLK, CHUNKS); each thread handles 4 columns (float4) x rpc rows.
__global__ void k_partial_abssum(const float4* __restrict__ x4,
                                 float4* __restrict__ partial4,
                                 int f4, int rows, int rpc) {
    int col4  = blockIdx.x * BLK + threadIdx.x;     // float4-column index
    int chunk = blockIdx.y;
    int r0 = chunk * rpc;
    int r1 = r0 + rpc;
    if (r1 > rows) r1 = rows;
    float4 s = make_float4(0.f, 0.f, 0.f, 0.f);
    for (int r = r0; r < r1; ++r) {
        float4 v = x4[(size_t)(1 + r) * f4 + col4]; // rows 1..K-1 (error terms)
        s.x += fabsf(v.x);
        s.y += fabsf(v.y);
        s.z += fabsf(v.z);
        s.w += fabsf(v.w);
    }
    partial4[(size_t)chunk * f4 + col4] = s;
}

// Kernel 2: reduce partials per column, compute scale[f] and half[f].
__global__ void k_finalize(const float* __restrict__ partial,
                           int chunks,
                           const float* __restrict__ x,        // row 0 = center
                           const float* __restrict__ lambdas,
                           float* __restrict__ scale,
                           float* __restrict__ half_,
                           int F) {
    int col = blockIdx.x * BLK + threadIdx.x;
    if (col >= F) return;
    float s = 0.f;
    for (int c = 0; c < chunks; ++c)
        s += partial[(size_t)c * F + col];
    float cen = x[col];
    float l = cen - s;
    float u = cen + s;
    float la = lambdas[col];
    float pos   = (l > 0.f) ? 1.f : 0.f;
    float cross = (u > 0.f && l < 0.f) ? 1.f : 0.f;
    float d = fmaxf(-l * la, u * (1.f - la));
    scale[col] = pos + cross * la;
    half_[col] = 0.5f * cross * d;
}

// Kernel 3: fused writer for the whole [K+F, F] output.
//   row <  K : out[row] = scale * x[row]  (+half on row 0)
//   row >= K : ext row (row-K): zeros, with half_[row-K] at column (row-K)
// grid = (f4/BLK, K+F); all stores nontemporal (write-once stream).
__global__ void k_write_all(const float4* __restrict__ x4,
                            const float4* __restrict__ scale4,
                            const float4* __restrict__ half4,
                            const float* __restrict__ half_,
                            v4f* __restrict__ out4,
                            int f4, int K) {
    int col4 = blockIdx.x * BLK + threadIdx.x;
    int row  = blockIdx.y;
    v4f o;
    if (row < K) {
        float4 v = x4[(size_t)row * f4 + col4];
        float4 s = scale4[col4];
        o.x = v.x * s.x;
        o.y = v.y * s.y;
        o.z = v.z * s.z;
        o.w = v.w * s.w;
        if (row == 0) {
            float4 h = half4[col4];
            o.x += h.x; o.y += h.y; o.z += h.z; o.w += h.w;
        }
    } else {
        int er = row - K;                 // ext-row index == diag column
        o = (v4f){0.f, 0.f, 0.f, 0.f};
        if (col4 == (er >> 2)) {
            o[er & 3] = half_[er];        // broadcast load, one block per row
        }
    }
    __builtin_nontemporal_store(o, &out4[(size_t)row * f4 + col4]);
}

extern "C" void kernel_launch(void* const* d_in, const int* in_sizes, int n_in,
                              void* d_out, int out_size, void* d_ws, size_t ws_size,
                              hipStream_t stream) {
    const float* x       = (const float*)d_in[0];
    const float* lambdas = (const float*)d_in[1];

    const int F    = in_sizes[1];          // 8192
    const int K    = in_sizes[0] / F;      // 1025
    const int f4   = F / 4;                // 2048
    const int rows = K - 1;                // 1024 error-term rows

    const int CHUNKS = 64;
    const int rpc = (rows + CHUNKS - 1) / CHUNKS;   // 16

    // Workspace layout (floats): [half F][scale F][partials CHUNKS*F]
    float* wsf     = (float*)d_ws;
    float* half_   = wsf;
    float* scale   = wsf + F;
    float* partial = wsf + 2 * (size_t)F;

    float* out = (float*)d_out;

    const float4* x4 = (const float4*)x;

    // 1. partial |x| column sums
    k_partial_abssum<<<dim3(f4 / BLK, CHUNKS), BLK, 0, stream>>>(
        x4, (float4*)partial, f4, rows, rpc);

    // 2. reduce partials -> scale[F], half[F]
    k_finalize<<<dim3((F + BLK - 1) / BLK), BLK, 0, stream>>>(
        partial, CHUNKS, x, lambdas, scale, half_, F);

    // 3. one fused pass writing all (K+F) x F output elements
    k_write_all<<<dim3(f4 / BLK, K + F), BLK, 0, stream>>>(
        x4, (const float4*)scale, (const float4*)half_, half_,
        (v4f*)out, f4, K);
}